// Round 3
// baseline (15517.509 us; speedup 1.0000x reference)
//
#include <hip/hip_runtime.h>
#include <cmath>

#define Bdim 4096
#define Tdim 16
#define Fdim 512
#define Udim 512
#define Mdim 8
#define Kdim 1024   // F + U
#define OUTdim 3

// ln_tau_m = m * 0.5*ln(10)
__device__ __constant__ float c_lntau[8] = {
  0.0f, 1.15129254649702286f, 2.30258509299404572f, 3.45387763949106858f,
  4.60517018598809144f, 5.75646273248511430f, 6.90775527898213716f, 8.05904782547916002f
};
// decay_m = exp(-0.04 / (10^(m/2) + 1e-7)), fp32-chain equivalent
__device__ __constant__ float c_decay[8] = {
  0.96078944f, 0.98743055f, 0.99600799f, 0.99873589f,
  0.99960008f, 0.99987352f, 0.99996000f, 0.99998735f
};

// ---------------------------------------------------------------------------
// GEMM over fused=[x_t, h_prev] (4096 x 1024) @ [Wr | Ws] (1024 x 8192).
// 128x128 tile, BK=8, 256 threads, 8x8 per-thread accumulators.
// Each thread owns 8 CONSECUTIVE columns = one full u-group (M=8), so the
// softmax over M is register-local in the epilogue.
//   r-part (block col < 4096): ctx[b,u] = sum_m softmax(-(v-lntau)^2)_m * h_hat[b,u,m]
//   s-part: s_buf[b,u,m] = softmax value
// ---------------------------------------------------------------------------
__global__ __launch_bounds__(256)
void gemm_rs(const float* __restrict__ x, const float* __restrict__ hprev, int has_h,
             const float* __restrict__ Wr, const float* __restrict__ br,
             const float* __restrict__ Ws, const float* __restrict__ bs,
             const float* __restrict__ h_hat, float* __restrict__ ctx,
             float* __restrict__ s_buf, int t)
{
  __shared__ __align__(16) float As[8][128];
  __shared__ __align__(16) float Bs[8][128];
  const int tid = threadIdx.x;
  const int m0  = blockIdx.y * 128;          // row (batch) base
  const int n0g = blockIdx.x * 128;          // global col in [0, 8192)
  const bool is_s = (n0g >= Udim * Mdim);
  const int n0 = is_s ? (n0g - Udim * Mdim) : n0g;   // col within Wr or Ws
  const float* __restrict__ Wmat = is_s ? Ws : Wr;
  const float* __restrict__ bias = is_s ? bs : br;

  // loader mapping
  const int ar   = tid >> 1;          // 0..127  A row in tile
  const int ac   = (tid & 1) * 4;     // 0 or 4  A col (k) base
  const int brow = tid >> 5;          // 0..7    B row (k)
  const int bcol = (tid & 31) * 4;    // 0..124  B col

  const int gb = m0 + ar;             // global batch row this thread loads
  const float* xrow = x + ((size_t)gb * Tdim + t) * Fdim;
  const float* hrow = hprev + (size_t)gb * Udim;

  float acc[8][8];
#pragma unroll
  for (int i = 0; i < 8; ++i)
#pragma unroll
    for (int j = 0; j < 8; ++j) acc[i][j] = 0.0f;

  const int ty = tid >> 4;   // 0..15 row group (8 rows)
  const int tx = tid & 15;   // 0..15 col group (8 consecutive cols)

  for (int k0 = 0; k0 < Kdim; k0 += 8) {
    const int k = k0 + ac;
    float4 av;
    if (k < Fdim) {
      av = *(const float4*)(xrow + k);
    } else if (has_h) {
      av = *(const float4*)(hrow + (k - Fdim));
    } else {
      av = make_float4(0.f, 0.f, 0.f, 0.f);
    }
    const float4 bv = *(const float4*)(Wmat + (size_t)(k0 + brow) * (Udim * Mdim) + (n0 + bcol));
    __syncthreads();
    As[ac + 0][ar] = av.x; As[ac + 1][ar] = av.y;
    As[ac + 2][ar] = av.z; As[ac + 3][ar] = av.w;
    *(float4*)&Bs[brow][bcol] = bv;
    __syncthreads();
#pragma unroll
    for (int kk = 0; kk < 8; ++kk) {
      float a[8], b[8];
      *(float4*)&a[0] = *(const float4*)&As[kk][ty * 8];
      *(float4*)&a[4] = *(const float4*)&As[kk][ty * 8 + 4];
      *(float4*)&b[0] = *(const float4*)&Bs[kk][tx * 8];
      *(float4*)&b[4] = *(const float4*)&Bs[kk][tx * 8 + 4];
#pragma unroll
      for (int i = 0; i < 8; ++i)
#pragma unroll
        for (int j = 0; j < 8; ++j)
          acc[i][j] = fmaf(a[i], b[j], acc[i][j]);
    }
  }

  // ---- epilogue: softmax over the 8 columns (= M) this thread owns ----
  const int ucol = n0 + tx * 8;       // region-local col base, multiple of 8
  const int u = ucol >> 3;
  float bvals[8];
#pragma unroll
  for (int j = 0; j < 8; ++j) bvals[j] = bias[ucol + j];

#pragma unroll
  for (int i = 0; i < 8; ++i) {
    const int bidx = m0 + ty * 8 + i;
    float z[8]; float zmax = -3.4e38f;
#pragma unroll
    for (int j = 0; j < 8; ++j) {
      const float v = acc[i][j] + bvals[j];
      const float d = v - c_lntau[j];
      z[j] = -d * d;
      zmax = fmaxf(zmax, z[j]);
    }
    float e[8]; float sum = 0.f;
#pragma unroll
    for (int j = 0; j < 8; ++j) { e[j] = expf(z[j] - zmax); sum += e[j]; }
    const float inv = 1.0f / sum;
    if (!is_s) {
      const float* hh = h_hat + ((size_t)bidx * Udim + u) * Mdim;
      const float4 h0 = *(const float4*)hh;
      const float4 h1 = *(const float4*)(hh + 4);
      const float c = e[0]*h0.x + e[1]*h0.y + e[2]*h0.z + e[3]*h0.w
                    + e[4]*h1.x + e[5]*h1.y + e[6]*h1.z + e[7]*h1.w;
      ctx[(size_t)bidx * Udim + u] = c * inv;
    } else {
      float* sp = s_buf + ((size_t)bidx * Udim + u) * Mdim;
      *(float4*)sp       = make_float4(e[0]*inv, e[1]*inv, e[2]*inv, e[3]*inv);
      *(float4*)(sp + 4) = make_float4(e[4]*inv, e[5]*inv, e[6]*inv, e[7]*inv);
    }
  }
}

// ---------------------------------------------------------------------------
// GEMM over fused2=[x_t, ctx] (4096 x 1024) @ Wq (1024 x 512), tanh epilogue.
// ---------------------------------------------------------------------------
__global__ __launch_bounds__(256)
void gemm_q(const float* __restrict__ x, const float* __restrict__ ctx,
            const float* __restrict__ Wq, const float* __restrict__ bq,
            float* __restrict__ q, int t)
{
  __shared__ __align__(16) float As[8][128];
  __shared__ __align__(16) float Bs[8][128];
  const int tid = threadIdx.x;
  const int m0 = blockIdx.y * 128;
  const int n0 = blockIdx.x * 128;

  const int ar   = tid >> 1;
  const int ac   = (tid & 1) * 4;
  const int brow = tid >> 5;
  const int bcol = (tid & 31) * 4;

  const int gb = m0 + ar;
  const float* xrow = x + ((size_t)gb * Tdim + t) * Fdim;
  const float* crow = ctx + (size_t)gb * Udim;

  float acc[8][8];
#pragma unroll
  for (int i = 0; i < 8; ++i)
#pragma unroll
    for (int j = 0; j < 8; ++j) acc[i][j] = 0.0f;

  const int ty = tid >> 4;
  const int tx = tid & 15;

  for (int k0 = 0; k0 < Kdim; k0 += 8) {
    const int k = k0 + ac;
    const float4 av = (k < Fdim) ? *(const float4*)(xrow + k)
                                 : *(const float4*)(crow + (k - Fdim));
    const float4 bv = *(const float4*)(Wq + (size_t)(k0 + brow) * Udim + (n0 + bcol));
    __syncthreads();
    As[ac + 0][ar] = av.x; As[ac + 1][ar] = av.y;
    As[ac + 2][ar] = av.z; As[ac + 3][ar] = av.w;
    *(float4*)&Bs[brow][bcol] = bv;
    __syncthreads();
#pragma unroll
    for (int kk = 0; kk < 8; ++kk) {
      float a[8], b[8];
      *(float4*)&a[0] = *(const float4*)&As[kk][ty * 8];
      *(float4*)&a[4] = *(const float4*)&As[kk][ty * 8 + 4];
      *(float4*)&b[0] = *(const float4*)&Bs[kk][tx * 8];
      *(float4*)&b[4] = *(const float4*)&Bs[kk][tx * 8 + 4];
#pragma unroll
      for (int i = 0; i < 8; ++i)
#pragma unroll
        for (int j = 0; j < 8; ++j)
          acc[i][j] = fmaf(a[i], b[j], acc[i][j]);
    }
  }

  const int col = n0 + tx * 8;
#pragma unroll
  for (int i = 0; i < 8; ++i) {
    const int bidx = m0 + ty * 8 + i;
    float4 q0, q1;
    q0.x = tanhf(acc[i][0] + bq[col + 0]);
    q0.y = tanhf(acc[i][1] + bq[col + 1]);
    q0.z = tanhf(acc[i][2] + bq[col + 2]);
    q0.w = tanhf(acc[i][3] + bq[col + 3]);
    q1.x = tanhf(acc[i][4] + bq[col + 4]);
    q1.y = tanhf(acc[i][5] + bq[col + 5]);
    q1.z = tanhf(acc[i][6] + bq[col + 6]);
    q1.w = tanhf(acc[i][7] + bq[col + 7]);
    *(float4*)(q + (size_t)bidx * Udim + col)     = q0;
    *(float4*)(q + (size_t)bidx * Udim + col + 4) = q1;
  }
}

// ---------------------------------------------------------------------------
// h_hat = ((1-s)*h_hat + s*q) * decay ;  h[b,u] = sum_m h_hat
// one thread per (b,u)
// ---------------------------------------------------------------------------
__global__ __launch_bounds__(256)
void update_kernel(float* __restrict__ h_hat, const float* __restrict__ s_buf,
                   const float* __restrict__ q, float* __restrict__ h)
{
  const int idx = blockIdx.x * 256 + threadIdx.x;   // (b,u) pair, exact grid
  const float qv = q[idx];
  const float* sp = s_buf + (size_t)idx * Mdim;
  float*       hp = h_hat + (size_t)idx * Mdim;
  const float4 s0 = *(const float4*)sp;
  const float4 s1 = *(const float4*)(sp + 4);
  const float4 h0 = *(const float4*)hp;
  const float4 h1 = *(const float4*)(hp + 4);
  float sv[8] = {s0.x, s0.y, s0.z, s0.w, s1.x, s1.y, s1.z, s1.w};
  float hv[8] = {h0.x, h0.y, h0.z, h0.w, h1.x, h1.y, h1.z, h1.w};
  float sum = 0.f;
#pragma unroll
  for (int m = 0; m < 8; ++m) {
    const float nh = ((1.0f - sv[m]) * hv[m] + sv[m] * qv) * c_decay[m];
    hv[m] = nh;
    sum += nh;
  }
  *(float4*)hp       = make_float4(hv[0], hv[1], hv[2], hv[3]);
  *(float4*)(hp + 4) = make_float4(hv[4], hv[5], hv[6], hv[7]);
  h[idx] = sum;
}

// ---------------------------------------------------------------------------
// out[b,t,:] = h[b,:] @ Wo + bo    (one wave per batch row, shuffle reduce)
// ---------------------------------------------------------------------------
__global__ __launch_bounds__(64)
void out_step(const float* __restrict__ h, const float* __restrict__ Wo,
              const float* __restrict__ bo, float* __restrict__ out, int t)
{
  const int b = blockIdx.x;
  const int lane = threadIdx.x;
  const float* hr = h + (size_t)b * Udim;
  float a0 = 0.f, a1 = 0.f, a2 = 0.f;
#pragma unroll
  for (int u0 = 0; u0 < Udim; u0 += 64) {
    const float hv = hr[u0 + lane];
    const float* w = Wo + (size_t)(u0 + lane) * 3;
    a0 = fmaf(hv, w[0], a0);
    a1 = fmaf(hv, w[1], a1);
    a2 = fmaf(hv, w[2], a2);
  }
#pragma unroll
  for (int off = 32; off; off >>= 1) {
    a0 += __shfl_down(a0, off);
    a1 += __shfl_down(a1, off);
    a2 += __shfl_down(a2, off);
  }
  if (lane == 0) {
    float* o = out + ((size_t)b * Tdim + t) * 3;
    o[0] = a0 + bo[0];
    o[1] = a1 + bo[1];
    o[2] = a2 + bo[2];
  }
}

__global__ __launch_bounds__(256)
void zero_kernel(float4* __restrict__ p, size_t n4)
{
  const size_t i = (size_t)blockIdx.x * 256 + threadIdx.x;
  const size_t stride = (size_t)gridDim.x * 256;
  for (size_t j = i; j < n4; j += stride)
    p[j] = make_float4(0.f, 0.f, 0.f, 0.f);
}

extern "C" void kernel_launch(void* const* d_in, const int* in_sizes, int n_in,
                              void* d_out, int out_size, void* d_ws, size_t ws_size,
                              hipStream_t stream)
{
  const float* x  = (const float*)d_in[0];
  const float* Wr = (const float*)d_in[1];
  const float* br = (const float*)d_in[2];
  const float* Wq = (const float*)d_in[3];
  const float* bq = (const float*)d_in[4];
  const float* Ws = (const float*)d_in[5];
  const float* bs = (const float*)d_in[6];
  const float* Wo = (const float*)d_in[7];
  const float* bo = (const float*)d_in[8];
  float* out = (float*)d_out;

  // workspace layout (floats):
  //   hhat: B*U*M = 16,777,216
  //   sbuf: B*U*M = 16,777,216
  //   h:    B*U   =  2,097,152
  //   ctx:  B*U   =  2,097,152
  //   qb:   B*U   =  2,097,152
  // total 39,845,888 floats = 159.4 MB
  const size_t need = (size_t)39845888 * sizeof(float);
  if (ws_size < need) return;   // not enough scratch: fail validation, not the GPU

  float* ws   = (float*)d_ws;
  float* hhat = ws;
  float* sbuf = hhat + (size_t)Bdim * Udim * Mdim;
  float* h    = sbuf + (size_t)Bdim * Udim * Mdim;
  float* ctx  = h    + (size_t)Bdim * Udim;
  float* qb   = ctx  + (size_t)Bdim * Udim;

  // h_hat starts at zero (ws is poisoned 0xAA by the harness)
  zero_kernel<<<4096, 256, 0, stream>>>((float4*)hhat, (size_t)Bdim * Udim * Mdim / 4);

  for (int t = 0; t < Tdim; ++t) {
    dim3 g1(64, 32);   // 8192/128 cols, 4096/128 rows
    gemm_rs<<<g1, 256, 0, stream>>>(x, h, (t > 0) ? 1 : 0,
                                    Wr, br, Ws, bs, hhat, ctx, sbuf, t);
    dim3 g2(4, 32);    // 512/128 cols
    gemm_q<<<g2, 256, 0, stream>>>(x, ctx, Wq, bq, qb, t);
    update_kernel<<<(Bdim * Udim) / 256, 256, 0, stream>>>(hhat, sbuf, qb, h);
    out_step<<<Bdim, 64, 0, stream>>>(h, Wo, bo, out, t);
  }
}

// Round 4
// 6715.421 us; speedup vs baseline: 2.3107x; 2.3107x over previous
//
#include <hip/hip_runtime.h>
#include <hip/hip_fp16.h>
#include <cmath>

#define Bdim 4096
#define Tdim 16
#define Fdim 512
#define Udim 512
#define Mdim 8
#define Kdim 1024   // F + U
#define Ndim 8192   // U*M*2 (r-region 0..4095, s-region 4096..8191)

typedef __attribute__((ext_vector_type(8))) short bf16x8;
typedef __attribute__((ext_vector_type(4))) float f32x4;
typedef __attribute__((address_space(1))) const void* as1_cvp;
typedef __attribute__((address_space(3))) void* as3_vp;

// ln_tau_m = m * 0.5*ln(10)   (f64 computed, rounded to f32 — matched ref in R3)
__device__ __constant__ float c_lntau[8] = {
  0.0f, 1.15129254649702286f, 2.30258509299404572f, 3.45387763949106858f,
  4.60517018598809144f, 5.75646273248511430f, 6.90775527898213716f, 8.05904782547916002f
};
__device__ __constant__ float c_decay[8] = {
  0.96078944f, 0.98743055f, 0.99600799f, 0.99873589f,
  0.99960008f, 0.99987352f, 0.99996000f, 0.99998735f
};

// fp32 -> bf16 RNE
__device__ __forceinline__ unsigned short f2bf(float f) {
  unsigned u = __float_as_uint(f);
  return (unsigned short)((u + 0x7fffu + ((u >> 16) & 1u)) >> 16);
}
// split fp32 x8 into hi/lo bf16x8 and store to LDS
__device__ __forceinline__ void cvt_store8(float4 a, float4 b, short* ph, short* pl) {
  float f[8] = {a.x, a.y, a.z, a.w, b.x, b.y, b.z, b.w};
  bf16x8 hv, lv;
#pragma unroll
  for (int j = 0; j < 8; ++j) {
    unsigned short h = f2bf(f[j]);
    hv[j] = (short)h;
    float r = f[j] - __uint_as_float((unsigned)h << 16);
    lv[j] = (short)f2bf(r);
  }
  *(bf16x8*)ph = hv;
  *(bf16x8*)pl = lv;
}

#define GLOAD16(gp, lp) __builtin_amdgcn_global_load_lds((as1_cvp)(gp), (as3_vp)(lp), 16, 0, 0)

// ---------------------------------------------------------------------------
// W transpose + hi/lo split:  W [1024][ldw] fp32  ->  WT_hi/WT_lo [n][1024] bf16
// 64x64 tiles via LDS. dest row = n_off + global n.
// ---------------------------------------------------------------------------
__global__ __launch_bounds__(256)
void wconv(const float* __restrict__ W, int ldw,
           short* __restrict__ WT_hi, short* __restrict__ WT_lo, int n_off)
{
  __shared__ float tile[64][65];
  const int tid = threadIdx.x;
  const int n0 = blockIdx.x * 64, k0 = blockIdx.y * 64;
#pragma unroll 4
  for (int i = 0; i < 16; ++i) {
    const int kl = i * 4 + (tid >> 6), nl = tid & 63;
    tile[kl][nl] = W[(size_t)(k0 + kl) * ldw + (n0 + nl)];
  }
  __syncthreads();
#pragma unroll 4
  for (int i = 0; i < 16; ++i) {
    const int nl = i * 4 + (tid >> 6), kl = tid & 63;
    const float v = tile[kl][nl];
    const unsigned short h = f2bf(v);
    const float r = v - __uint_as_float((unsigned)h << 16);
    const size_t di = (size_t)(n_off + n0 + nl) * 1024 + (k0 + kl);
    WT_hi[di] = (short)h;
    WT_lo[di] = (short)f2bf(r);
  }
}

// ---------------------------------------------------------------------------
// gemm_rs: C = [x_t | h] @ [Wr | Ws]  via bf16x2-split MFMA, 128x128 tile,
// BK=32, 4 waves (2x2), per-wave 64x64 = 4x4 fragments 16x16x32.
// A reg-staged (fp32 -> hi/lo bf16 in-flight), B via global_load_lds of
// pre-transposed/split WT. Epilogue: softmax over M (8 adjacent lanes).
// ---------------------------------------------------------------------------
__global__ __launch_bounds__(256)
void gemm_rs_mfma(const float* __restrict__ x, const float* __restrict__ h, int has_h,
                  const short* __restrict__ WT_hi, const short* __restrict__ WT_lo,
                  const float* __restrict__ br, const float* __restrict__ bs,
                  const float* __restrict__ h_hat, float* __restrict__ ctx,
                  __half* __restrict__ sbuf, int t)
{
  __shared__ short Ah[128 * 32], Al[128 * 32], Bh[128 * 32], Bl[128 * 32];
  const int tid = threadIdx.x, lane = tid & 63, wid = tid >> 6;
  const int m0 = blockIdx.y * 128, n0 = blockIdx.x * 128;
  const int wm = wid >> 1, wn = wid & 1;

  // A staging mapping: 2 threads/row, 16 k per thread
  const int s_row = tid >> 1, s_kb = (tid & 1) * 16;
  const float* xrow = x + ((size_t)(m0 + s_row) * Tdim + t) * Fdim;
  const float* hrow = h + (size_t)(m0 + s_row) * Udim;

  f32x4 acc[4][4];
#pragma unroll
  for (int i = 0; i < 4; ++i)
#pragma unroll
    for (int j = 0; j < 4; ++j) acc[i][j] = 0.0f;

  for (int k0 = 0; k0 < Kdim; k0 += 32) {
    // ---- A tile fp32 loads (regs) ----
    float4 va0, va1, va2, va3;
    if (k0 < Fdim) {
      const float* s = xrow + k0 + s_kb;
      va0 = *(const float4*)s; va1 = *(const float4*)(s + 4);
      va2 = *(const float4*)(s + 8); va3 = *(const float4*)(s + 12);
    } else if (has_h) {
      const float* s = hrow + (k0 - Fdim) + s_kb;
      va0 = *(const float4*)s; va1 = *(const float4*)(s + 4);
      va2 = *(const float4*)(s + 8); va3 = *(const float4*)(s + 12);
    } else {
      va0 = va1 = va2 = va3 = make_float4(0.f, 0.f, 0.f, 0.f);
    }
    __syncthreads();   // previous iter's frag reads complete
    // ---- A convert + LDS write ----
    cvt_store8(va0, va1, &Ah[s_row * 32 + s_kb],     &Al[s_row * 32 + s_kb]);
    cvt_store8(va2, va3, &Ah[s_row * 32 + s_kb + 8], &Al[s_row * 32 + s_kb + 8]);
    // ---- B tiles via global_load_lds (wave-uniform LDS base + lane*16) ----
#pragma unroll
    for (int i = 0; i < 2; ++i) {
      const int nrow = wid * 32 + i * 16;       // n-local base for this issue
      const size_t gb = ((size_t)(n0 + nrow + (lane >> 2)) * 1024 + k0) * 2 + (size_t)(lane & 3) * 16;
      GLOAD16((const char*)WT_hi + gb, (char*)Bh + nrow * 64);
      GLOAD16((const char*)WT_lo + gb, (char*)Bl + nrow * 64);
    }
    __syncthreads();   // staging visible (compiler drains vmcnt/lgkm)
    // ---- fragments + 48 MFMA ----
    const int kg = lane >> 4, fr = lane & 15;
    bf16x8 ah[4], al[4], bh[4], bl[4];
#pragma unroll
    for (int mi = 0; mi < 4; ++mi) {
      const int row = wm * 64 + mi * 16 + fr;
      ah[mi] = *(const bf16x8*)&Ah[row * 32 + kg * 8];
      al[mi] = *(const bf16x8*)&Al[row * 32 + kg * 8];
    }
#pragma unroll
    for (int nj = 0; nj < 4; ++nj) {
      const int row = wn * 64 + nj * 16 + fr;
      bh[nj] = *(const bf16x8*)&Bh[row * 32 + kg * 8];
      bl[nj] = *(const bf16x8*)&Bl[row * 32 + kg * 8];
    }
#pragma unroll
    for (int mi = 0; mi < 4; ++mi)
#pragma unroll
      for (int nj = 0; nj < 4; ++nj) {
        acc[mi][nj] = __builtin_amdgcn_mfma_f32_16x16x32_bf16(ah[mi], bh[nj], acc[mi][nj], 0, 0, 0);
        acc[mi][nj] = __builtin_amdgcn_mfma_f32_16x16x32_bf16(ah[mi], bl[nj], acc[mi][nj], 0, 0, 0);
        acc[mi][nj] = __builtin_amdgcn_mfma_f32_16x16x32_bf16(al[mi], bh[nj], acc[mi][nj], 0, 0, 0);
      }
  }

  // ---- epilogue: softmax over M within 8-lane groups ----
  const bool is_s = (n0 >= Udim * Mdim);
  const float* bias = is_s ? bs : br;
  const int nb = is_s ? n0 - Udim * Mdim : n0;
  const float lnt = c_lntau[lane & 7];
  float bv[4];
#pragma unroll
  for (int nj = 0; nj < 4; ++nj) bv[nj] = bias[nb + wn * 64 + nj * 16 + (lane & 15)];

#pragma unroll
  for (int mi = 0; mi < 4; ++mi)
#pragma unroll
    for (int nj = 0; nj < 4; ++nj)
#pragma unroll
      for (int r = 0; r < 4; ++r) {
        const int brow = m0 + wm * 64 + mi * 16 + (lane >> 4) * 4 + r;
        const int ncol = nb + wn * 64 + nj * 16 + (lane & 15);
        const float v = acc[mi][nj][r] + bv[nj];
        const float d = v - lnt;
        float z = -d * d;
        float zm = z;
        zm = fmaxf(zm, __shfl_xor(zm, 1));
        zm = fmaxf(zm, __shfl_xor(zm, 2));
        zm = fmaxf(zm, __shfl_xor(zm, 4));
        const float e = expf(z - zm);
        float den = e;
        den += __shfl_xor(den, 1);
        den += __shfl_xor(den, 2);
        den += __shfl_xor(den, 4);
        const int u = ncol >> 3;
        if (!is_s) {
          const float hh = h_hat[((size_t)brow * Udim + u) * Mdim + (lane & 7)];
          float num = e * hh;
          num += __shfl_xor(num, 1);
          num += __shfl_xor(num, 2);
          num += __shfl_xor(num, 4);
          if ((lane & 7) == 0) ctx[(size_t)brow * Udim + u] = num / den;
        } else {
          sbuf[((size_t)brow * Udim + u) * Mdim + (lane & 7)] = __float2half(e / den);
        }
      }
}

// ---------------------------------------------------------------------------
// gemm_q: q = tanh([x_t | ctx] @ Wq + bq), fused state update in epilogue:
//   h_hat = ((1-s)h_hat + s q) * decay ;  h[b,u] = sum_m h_hat
// 64x128 tile, BK=32, 4 waves (2x2), per-wave 32x64 = 2x4 fragments.
// ---------------------------------------------------------------------------
__global__ __launch_bounds__(256)
void gemm_q_mfma(const float* __restrict__ x, const float* __restrict__ ctx,
                 const short* __restrict__ WqT_hi, const short* __restrict__ WqT_lo,
                 const float* __restrict__ bq, const __half* __restrict__ sbuf,
                 float* __restrict__ h_hat, float* __restrict__ hbuf, int t)
{
  __shared__ short Ah[64 * 32], Al[64 * 32], Bh[128 * 32], Bl[128 * 32];
  const int tid = threadIdx.x, lane = tid & 63, wid = tid >> 6;
  const int m0 = blockIdx.y * 64, n0 = blockIdx.x * 128;
  const int wm = wid >> 1, wn = wid & 1;

  const int s_row = tid >> 2, s_kb = (tid & 3) * 8;   // 4 threads/row, 8 k each
  const float* xrow = x + ((size_t)(m0 + s_row) * Tdim + t) * Fdim;
  const float* crow = ctx + (size_t)(m0 + s_row) * Udim;

  f32x4 acc[2][4];
#pragma unroll
  for (int i = 0; i < 2; ++i)
#pragma unroll
    for (int j = 0; j < 4; ++j) acc[i][j] = 0.0f;

  for (int k0 = 0; k0 < Kdim; k0 += 32) {
    float4 va0, va1;
    if (k0 < Fdim) {
      const float* s = xrow + k0 + s_kb;
      va0 = *(const float4*)s; va1 = *(const float4*)(s + 4);
    } else {
      const float* s = crow + (k0 - Fdim) + s_kb;
      va0 = *(const float4*)s; va1 = *(const float4*)(s + 4);
    }
    __syncthreads();
    cvt_store8(va0, va1, &Ah[s_row * 32 + s_kb], &Al[s_row * 32 + s_kb]);
#pragma unroll
    for (int i = 0; i < 2; ++i) {
      const int nrow = wid * 32 + i * 16;
      const size_t gb = ((size_t)(n0 + nrow + (lane >> 2)) * 1024 + k0) * 2 + (size_t)(lane & 3) * 16;
      GLOAD16((const char*)WqT_hi + gb, (char*)Bh + nrow * 64);
      GLOAD16((const char*)WqT_lo + gb, (char*)Bl + nrow * 64);
    }
    __syncthreads();
    const int kg = lane >> 4, fr = lane & 15;
    bf16x8 ah[2], al[2], bh[4], bl[4];
#pragma unroll
    for (int mi = 0; mi < 2; ++mi) {
      const int row = wm * 32 + mi * 16 + fr;
      ah[mi] = *(const bf16x8*)&Ah[row * 32 + kg * 8];
      al[mi] = *(const bf16x8*)&Al[row * 32 + kg * 8];
    }
#pragma unroll
    for (int nj = 0; nj < 4; ++nj) {
      const int row = wn * 64 + nj * 16 + fr;
      bh[nj] = *(const bf16x8*)&Bh[row * 32 + kg * 8];
      bl[nj] = *(const bf16x8*)&Bl[row * 32 + kg * 8];
    }
#pragma unroll
    for (int mi = 0; mi < 2; ++mi)
#pragma unroll
      for (int nj = 0; nj < 4; ++nj) {
        acc[mi][nj] = __builtin_amdgcn_mfma_f32_16x16x32_bf16(ah[mi], bh[nj], acc[mi][nj], 0, 0, 0);
        acc[mi][nj] = __builtin_amdgcn_mfma_f32_16x16x32_bf16(ah[mi], bl[nj], acc[mi][nj], 0, 0, 0);
        acc[mi][nj] = __builtin_amdgcn_mfma_f32_16x16x32_bf16(al[mi], bh[nj], acc[mi][nj], 0, 0, 0);
      }
  }

  // ---- epilogue: tanh + fused h_hat update ----
  float bv[4];
#pragma unroll
  for (int nj = 0; nj < 4; ++nj) bv[nj] = bq[n0 + wn * 64 + nj * 16 + (lane & 15)];

#pragma unroll
  for (int mi = 0; mi < 2; ++mi)
#pragma unroll
    for (int nj = 0; nj < 4; ++nj)
#pragma unroll
      for (int r = 0; r < 4; ++r) {
        const int b = m0 + wm * 32 + mi * 16 + (lane >> 4) * 4 + r;
        const int u = n0 + wn * 64 + nj * 16 + (lane & 15);
        const float qv = tanhf(acc[mi][nj][r] + bv[nj]);
        const size_t base = ((size_t)b * Udim + u) * Mdim;
        const __half2* sp = (const __half2*)(sbuf + base);
        const __half2 s01 = sp[0], s23 = sp[1], s45 = sp[2], s67 = sp[3];
        float sv[8] = {__low2float(s01), __high2float(s01), __low2float(s23), __high2float(s23),
                       __low2float(s45), __high2float(s45), __low2float(s67), __high2float(s67)};
        const float4 h0 = *(const float4*)(h_hat + base);
        const float4 h1 = *(const float4*)(h_hat + base + 4);
        float hv[8] = {h0.x, h0.y, h0.z, h0.w, h1.x, h1.y, h1.z, h1.w};
        float sum = 0.f;
#pragma unroll
        for (int m = 0; m < 8; ++m) {
          const float nh = ((1.0f - sv[m]) * hv[m] + sv[m] * qv) * c_decay[m];
          hv[m] = nh;
          sum += nh;
        }
        *(float4*)(h_hat + base)     = make_float4(hv[0], hv[1], hv[2], hv[3]);
        *(float4*)(h_hat + base + 4) = make_float4(hv[4], hv[5], hv[6], hv[7]);
        hbuf[(size_t)b * Udim + u] = sum;
      }
}

// ---------------------------------------------------------------------------
// out[b,t,:] = h[b,:] @ Wo + bo    (one wave per batch row)
// ---------------------------------------------------------------------------
__global__ __launch_bounds__(64)
void out_step(const float* __restrict__ h, const float* __restrict__ Wo,
              const float* __restrict__ bo, float* __restrict__ out, int t)
{
  const int b = blockIdx.x;
  const int lane = threadIdx.x;
  const float* hr = h + (size_t)b * Udim;
  float a0 = 0.f, a1 = 0.f, a2 = 0.f;
#pragma unroll
  for (int u0 = 0; u0 < Udim; u0 += 64) {
    const float hv = hr[u0 + lane];
    const float* w = Wo + (size_t)(u0 + lane) * 3;
    a0 = fmaf(hv, w[0], a0);
    a1 = fmaf(hv, w[1], a1);
    a2 = fmaf(hv, w[2], a2);
  }
#pragma unroll
  for (int off = 32; off; off >>= 1) {
    a0 += __shfl_down(a0, off);
    a1 += __shfl_down(a1, off);
    a2 += __shfl_down(a2, off);
  }
  if (lane == 0) {
    float* o = out + ((size_t)b * Tdim + t) * 3;
    o[0] = a0 + bo[0]; o[1] = a1 + bo[1]; o[2] = a2 + bo[2];
  }
}

__global__ __launch_bounds__(256)
void zero_kernel(float4* __restrict__ p, size_t n4)
{
  const size_t i = (size_t)blockIdx.x * 256 + threadIdx.x;
  const size_t stride = (size_t)gridDim.x * 256;
  for (size_t j = i; j < n4; j += stride)
    p[j] = make_float4(0.f, 0.f, 0.f, 0.f);
}

extern "C" void kernel_launch(void* const* d_in, const int* in_sizes, int n_in,
                              void* d_out, int out_size, void* d_ws, size_t ws_size,
                              hipStream_t stream)
{
  const float* x  = (const float*)d_in[0];
  const float* Wr = (const float*)d_in[1];
  const float* br = (const float*)d_in[2];
  const float* Wq = (const float*)d_in[3];
  const float* bq = (const float*)d_in[4];
  const float* Ws = (const float*)d_in[5];
  const float* bs = (const float*)d_in[6];
  const float* Wo = (const float*)d_in[7];
  const float* bo = (const float*)d_in[8];
  float* out = (float*)d_out;

  // ws layout (bytes):
  //   WT_hi  [8192][1024] bf16 : 16,777,216
  //   WT_lo                    : 16,777,216
  //   WqT_hi [512][1024]  bf16 :  1,048,576
  //   WqT_lo                   :  1,048,576
  //   h_hat  [B][U][M]    f32  : 67,108,864
  //   sbuf   [B][U][M]    f16  : 33,554,432
  //   h      [B][U]       f32  :  8,388,608
  //   ctx    [B][U]       f32  :  8,388,608
  // total 153,092,096 B  (<= 159,383,552 proven available in R3)
  const size_t need = 153092096;
  if (ws_size < need) return;

  char* p = (char*)d_ws;
  short* WT_hi  = (short*)p;               p += 16777216;
  short* WT_lo  = (short*)p;               p += 16777216;
  short* WqT_hi = (short*)p;               p += 1048576;
  short* WqT_lo = (short*)p;               p += 1048576;
  float* hhat   = (float*)p;               p += 67108864;
  __half* sbuf  = (__half*)p;              p += 33554432;
  float* h      = (float*)p;               p += 8388608;
  float* ctx    = (float*)p;               p += 8388608;

  zero_kernel<<<4096, 256, 0, stream>>>((float4*)hhat, (size_t)Bdim * Udim * Mdim / 4);

  // W transpose + split (once per launch)
  wconv<<<dim3(64, 16), 256, 0, stream>>>(Wr, 4096, WT_hi, WT_lo, 0);
  wconv<<<dim3(64, 16), 256, 0, stream>>>(Ws, 4096, WT_hi, WT_lo, 4096);
  wconv<<<dim3(8, 16),  256, 0, stream>>>(Wq, 512,  WqT_hi, WqT_lo, 0);

  for (int t = 0; t < Tdim; ++t) {
    gemm_rs_mfma<<<dim3(64, 32), 256, 0, stream>>>(x, h, (t > 0) ? 1 : 0,
                                                   WT_hi, WT_lo, br, bs,
                                                   hhat, ctx, sbuf, t);
    gemm_q_mfma<<<dim3(4, 64), 256, 0, stream>>>(x, ctx, WqT_hi, WqT_lo, bq,
                                                 sbuf, hhat, h, t);
    out_step<<<Bdim, 64, 0, stream>>>(h, Wo, bo, out, t);
  }
}

// Round 5
// 6619.309 us; speedup vs baseline: 2.3443x; 1.0145x over previous
//
#include <hip/hip_runtime.h>
#include <hip/hip_fp16.h>
#include <cmath>

#define Bdim 4096
#define Tdim 16
#define Fdim 512
#define Udim 512
#define Mdim 8
#define Kdim 1024   // F + U

typedef __attribute__((ext_vector_type(8))) short bf16x8;
typedef __attribute__((ext_vector_type(4))) float f32x4;
typedef __attribute__((address_space(1))) const void* as1_cvp;
typedef __attribute__((address_space(3))) void* as3_vp;

__device__ __constant__ float c_lntau[8] = {
  0.0f, 1.15129254649702286f, 2.30258509299404572f, 3.45387763949106858f,
  4.60517018598809144f, 5.75646273248511430f, 6.90775527898213716f, 8.05904782547916002f
};
__device__ __constant__ float c_decay[8] = {
  0.96078944f, 0.98743055f, 0.99600799f, 0.99873589f,
  0.99960008f, 0.99987352f, 0.99996000f, 0.99998735f
};

__device__ __forceinline__ unsigned short f2bf(float f) {
  unsigned u = __float_as_uint(f);
  return (unsigned short)((u + 0x7fffu + ((u >> 16) & 1u)) >> 16);
}
__device__ __forceinline__ float bf2f(unsigned short h) {
  return __uint_as_float((unsigned)h << 16);
}
// split fp32 x8 into hi/lo bf16x8 and store (works for LDS or global short*)
__device__ __forceinline__ void cvt_store8(float4 a, float4 b, short* ph, short* pl) {
  float f[8] = {a.x, a.y, a.z, a.w, b.x, b.y, b.z, b.w};
  bf16x8 hv, lv;
#pragma unroll
  for (int j = 0; j < 8; ++j) {
    unsigned short h = f2bf(f[j]);
    hv[j] = (short)h;
    lv[j] = (short)f2bf(f[j] - bf2f(h));
  }
  *(bf16x8*)ph = hv;
  *(bf16x8*)pl = lv;
}

#define GLOAD16(gp, lp) __builtin_amdgcn_global_load_lds((as1_cvp)(gp), (as3_vp)(lp), 16, 0, 0)

// ---------------------------------------------------------------------------
// W transpose + hi/lo split:  W [1024][ldw] fp32 -> WT_hi/WT_lo [n][1024] bf16
// ---------------------------------------------------------------------------
__global__ __launch_bounds__(256)
void wconv(const float* __restrict__ W, int ldw,
           short* __restrict__ WT_hi, short* __restrict__ WT_lo, int n_off)
{
  __shared__ float tile[64][65];
  const int tid = threadIdx.x;
  const int n0 = blockIdx.x * 64, k0 = blockIdx.y * 64;
#pragma unroll 4
  for (int i = 0; i < 16; ++i) {
    const int kl = i * 4 + (tid >> 6), nl = tid & 63;
    tile[kl][nl] = W[(size_t)(k0 + kl) * ldw + (n0 + nl)];
  }
  __syncthreads();
#pragma unroll 4
  for (int i = 0; i < 16; ++i) {
    const int nl = i * 4 + (tid >> 6), kl = tid & 63;
    const float v = tile[kl][nl];
    const unsigned short h = f2bf(v);
    const size_t di = (size_t)(n_off + n0 + nl) * 1024 + (k0 + kl);
    WT_hi[di] = (short)h;
    WT_lo[di] = (short)f2bf(v - bf2f(h));
  }
}

// split x[:,t,:] into A-buffer cols 0..511 (one block row b, 64 threads, 8 elems each)
__device__ __forceinline__ void xsplit_row(const float* x, short* Ahw, short* Alw,
                                           int b, int t, int j)
{
  const float* s = x + ((size_t)b * Tdim + t) * Fdim + j * 8;
  const float4 a = *(const float4*)s;
  const float4 c = *(const float4*)(s + 4);
  cvt_store8(a, c, Ahw + (size_t)b * Kdim + j * 8, Alw + (size_t)b * Kdim + j * 8);
}

__global__ __launch_bounds__(64)
void xsplit0(const float* __restrict__ x, short* Ahw, short* Alw)
{
  xsplit_row(x, Ahw, Alw, blockIdx.x, 0, threadIdx.x);
}

// ---------------------------------------------------------------------------
// gemm_rs: [x_t | h] @ [Wr | Ws] via 3-term bf16-split MFMA. 128x128 tile,
// BK=32, 4 waves (2x2), per-wave 64x64 = 4x4 frags 16x16x32. A and B both
// pre-split bf16 in global, staged via global_load_lds (no in-loop VALU cvt).
// Epilogue: softmax over M (8 adjacent lanes); r-part -> ctx (bf16 split),
// s-part -> sbuf (fp16).
// ---------------------------------------------------------------------------
__global__ __launch_bounds__(256)
void gemm_rs_mfma(const short* __restrict__ Ahg, const short* __restrict__ Alg,
                  const short* __restrict__ WTh, const short* __restrict__ WTl,
                  const float* __restrict__ br, const float* __restrict__ bs,
                  const float* __restrict__ h_hat, short* __restrict__ Ch,
                  short* __restrict__ Cl, __half* __restrict__ sbuf, int kmax)
{
  __shared__ short Ah[128 * 32], Al[128 * 32], Bh[128 * 32], Bl[128 * 32];
  const int tid = threadIdx.x, lane = tid & 63, wid = tid >> 6;
  const int m0 = blockIdx.y * 128, n0 = blockIdx.x * 128;
  const int wm = wid >> 1, wn = wid & 1;
  const int lrow16 = lane >> 2;        // row within a 16-row chunk
  const int lcb = (lane & 3) * 16;     // byte offset within 64B row slice

  f32x4 acc[4][4];
#pragma unroll
  for (int i = 0; i < 4; ++i)
#pragma unroll
    for (int j = 0; j < 4; ++j) acc[i][j] = 0.0f;

  for (int k0 = 0; k0 < kmax; k0 += 32) {
    __syncthreads();   // prev iter frag reads complete before overwrite
#pragma unroll
    for (int i = 0; i < 2; ++i) {
      const int rb = wid * 32 + i * 16;
      const size_t ga = ((size_t)(m0 + rb + lrow16) * Kdim + k0) * 2 + lcb;
      GLOAD16((const char*)Ahg + ga, (char*)Ah + rb * 64);
      GLOAD16((const char*)Alg + ga, (char*)Al + rb * 64);
      const size_t gw = ((size_t)(n0 + rb + lrow16) * Kdim + k0) * 2 + lcb;
      GLOAD16((const char*)WTh + gw, (char*)Bh + rb * 64);
      GLOAD16((const char*)WTl + gw, (char*)Bl + rb * 64);
    }
    __syncthreads();   // staging visible
    const int kg = lane >> 4, fr = lane & 15;
    bf16x8 ah[4], al[4], bh[4], bl[4];
#pragma unroll
    for (int mi = 0; mi < 4; ++mi) {
      const int row = wm * 64 + mi * 16 + fr;
      ah[mi] = *(const bf16x8*)&Ah[row * 32 + kg * 8];
      al[mi] = *(const bf16x8*)&Al[row * 32 + kg * 8];
    }
#pragma unroll
    for (int nj = 0; nj < 4; ++nj) {
      const int row = wn * 64 + nj * 16 + fr;
      bh[nj] = *(const bf16x8*)&Bh[row * 32 + kg * 8];
      bl[nj] = *(const bf16x8*)&Bl[row * 32 + kg * 8];
    }
#pragma unroll
    for (int mi = 0; mi < 4; ++mi)
#pragma unroll
      for (int nj = 0; nj < 4; ++nj) {
        acc[mi][nj] = __builtin_amdgcn_mfma_f32_16x16x32_bf16(ah[mi], bh[nj], acc[mi][nj], 0, 0, 0);
        acc[mi][nj] = __builtin_amdgcn_mfma_f32_16x16x32_bf16(ah[mi], bl[nj], acc[mi][nj], 0, 0, 0);
        acc[mi][nj] = __builtin_amdgcn_mfma_f32_16x16x32_bf16(al[mi], bh[nj], acc[mi][nj], 0, 0, 0);
      }
  }

  // ---- epilogue: softmax over M within 8-lane groups ----
  const bool is_s = (n0 >= Udim * Mdim);
  const float* bias = is_s ? bs : br;
  const int nb = is_s ? n0 - Udim * Mdim : n0;
  const float lnt = c_lntau[lane & 7];
  float bv[4];
#pragma unroll
  for (int nj = 0; nj < 4; ++nj) bv[nj] = bias[nb + wn * 64 + nj * 16 + (lane & 15)];

#pragma unroll
  for (int mi = 0; mi < 4; ++mi)
#pragma unroll
    for (int nj = 0; nj < 4; ++nj)
#pragma unroll
      for (int r = 0; r < 4; ++r) {
        const int brow = m0 + wm * 64 + mi * 16 + (lane >> 4) * 4 + r;
        const int ncol = nb + wn * 64 + nj * 16 + (lane & 15);
        const float v = acc[mi][nj][r] + bv[nj];
        const float d = v - lnt;
        float z = -d * d;
        float zm = z;
        zm = fmaxf(zm, __shfl_xor(zm, 1));
        zm = fmaxf(zm, __shfl_xor(zm, 2));
        zm = fmaxf(zm, __shfl_xor(zm, 4));
        const float e = expf(z - zm);
        float den = e;
        den += __shfl_xor(den, 1);
        den += __shfl_xor(den, 2);
        den += __shfl_xor(den, 4);
        const int u = ncol >> 3;
        if (!is_s) {
          const float hh = h_hat[((size_t)brow * Udim + u) * Mdim + (lane & 7)];
          float num = e * hh;
          num += __shfl_xor(num, 1);
          num += __shfl_xor(num, 2);
          num += __shfl_xor(num, 4);
          if ((lane & 7) == 0) {
            const float c = num / den;
            const unsigned short chh = f2bf(c);
            const size_t ci = (size_t)brow * Udim + u;
            Ch[ci] = (short)chh;
            Cl[ci] = (short)f2bf(c - bf2f(chh));
          }
        } else {
          sbuf[((size_t)brow * Udim + u) * Mdim + (lane & 7)] = __float2half(e / den);
        }
      }
}

// ---------------------------------------------------------------------------
// gemm_q: q = tanh([x_t | ctx] @ Wq + bq); fused h_hat update; writes h as
// bf16 split into A-buffer cols 512..1023. 64x128 tile, BK=32, 4 waves.
// A via global_load_lds (pre-split); B = Wq fp32, transpose+split in-loop.
// ---------------------------------------------------------------------------
__global__ __launch_bounds__(256)
void gemm_q_mfma(const short* Ahg, const short* Alg,
                 const short* Chg, const short* Clg,
                 const float* __restrict__ Wq, const float* __restrict__ bq,
                 const __half* __restrict__ sbuf, float* __restrict__ h_hat,
                 short* Ahw, short* Alw, int kmax)
{
  __shared__ short Ah[64 * 32], Al[64 * 32], Bh[128 * 32], Bl[128 * 32];
  const int tid = threadIdx.x, lane = tid & 63, wid = tid >> 6;
  const int m0 = blockIdx.y * 64, n0 = blockIdx.x * 128;
  const int wm = wid >> 1, wn = wid & 1;
  const int lrow16 = lane >> 2, lcb = (lane & 3) * 16;
  const int kr = tid & 31, ng = tid >> 5;

  f32x4 acc[2][4];
#pragma unroll
  for (int i = 0; i < 2; ++i)
#pragma unroll
    for (int j = 0; j < 4; ++j) acc[i][j] = 0.0f;

  for (int k0 = 0; k0 < kmax; k0 += 32) {
    __syncthreads();
    {   // A: one 16-row chunk per wave
      const int rb = wid * 16;
      if (k0 < Fdim) {
        const size_t ga = ((size_t)(m0 + rb + lrow16) * Kdim + k0) * 2 + lcb;
        GLOAD16((const char*)Ahg + ga, (char*)Ah + rb * 64);
        GLOAD16((const char*)Alg + ga, (char*)Al + rb * 64);
      } else {
        const size_t ga = ((size_t)(m0 + rb + lrow16) * Udim + (k0 - Fdim)) * 2 + lcb;
        GLOAD16((const char*)Chg + ga, (char*)Ah + rb * 64);
        GLOAD16((const char*)Clg + ga, (char*)Al + rb * 64);
      }
    }
    {   // B: fp32 Wq tile -> transpose + split into LDS
      const float* wp = Wq + (size_t)(k0 + kr) * Udim + n0 + ng * 16;
      const float4 w0 = *(const float4*)wp,      w1 = *(const float4*)(wp + 4);
      const float4 w2 = *(const float4*)(wp + 8), w3 = *(const float4*)(wp + 12);
      const float wv[16] = {w0.x, w0.y, w0.z, w0.w, w1.x, w1.y, w1.z, w1.w,
                            w2.x, w2.y, w2.z, w2.w, w3.x, w3.y, w3.z, w3.w};
#pragma unroll
      for (int i2 = 0; i2 < 16; ++i2) {
        const unsigned short hh = f2bf(wv[i2]);
        Bh[(ng * 16 + i2) * 32 + kr] = (short)hh;
        Bl[(ng * 16 + i2) * 32 + kr] = (short)f2bf(wv[i2] - bf2f(hh));
      }
    }
    __syncthreads();
    const int kg = lane >> 4, fr = lane & 15;
    bf16x8 ah[2], al[2], bh[4], bl[4];
#pragma unroll
    for (int mi = 0; mi < 2; ++mi) {
      const int row = wm * 32 + mi * 16 + fr;
      ah[mi] = *(const bf16x8*)&Ah[row * 32 + kg * 8];
      al[mi] = *(const bf16x8*)&Al[row * 32 + kg * 8];
    }
#pragma unroll
    for (int nj = 0; nj < 4; ++nj) {
      const int row = wn * 64 + nj * 16 + fr;
      bh[nj] = *(const bf16x8*)&Bh[row * 32 + kg * 8];
      bl[nj] = *(const bf16x8*)&Bl[row * 32 + kg * 8];
    }
#pragma unroll
    for (int mi = 0; mi < 2; ++mi)
#pragma unroll
      for (int nj = 0; nj < 4; ++nj) {
        acc[mi][nj] = __builtin_amdgcn_mfma_f32_16x16x32_bf16(ah[mi], bh[nj], acc[mi][nj], 0, 0, 0);
        acc[mi][nj] = __builtin_amdgcn_mfma_f32_16x16x32_bf16(ah[mi], bl[nj], acc[mi][nj], 0, 0, 0);
        acc[mi][nj] = __builtin_amdgcn_mfma_f32_16x16x32_bf16(al[mi], bh[nj], acc[mi][nj], 0, 0, 0);
      }
  }

  // ---- epilogue: tanh + fused h_hat update; h -> bf16 split A-cols ----
  float bv[4];
#pragma unroll
  for (int nj = 0; nj < 4; ++nj) bv[nj] = bq[n0 + wn * 64 + nj * 16 + (lane & 15)];

#pragma unroll
  for (int mi = 0; mi < 2; ++mi)
#pragma unroll
    for (int nj = 0; nj < 4; ++nj)
#pragma unroll
      for (int r = 0; r < 4; ++r) {
        const int b = m0 + wm * 32 + mi * 16 + (lane >> 4) * 4 + r;
        const int u = n0 + wn * 64 + nj * 16 + (lane & 15);
        const float qv = tanhf(acc[mi][nj][r] + bv[nj]);
        const size_t base = ((size_t)b * Udim + u) * Mdim;
        const __half2* sp = (const __half2*)(sbuf + base);
        const __half2 s01 = sp[0], s23 = sp[1], s45 = sp[2], s67 = sp[3];
        const float sv[8] = {__low2float(s01), __high2float(s01), __low2float(s23), __high2float(s23),
                             __low2float(s45), __high2float(s45), __low2float(s67), __high2float(s67)};
        const float4 h0 = *(const float4*)(h_hat + base);
        const float4 h1 = *(const float4*)(h_hat + base + 4);
        float hv[8] = {h0.x, h0.y, h0.z, h0.w, h1.x, h1.y, h1.z, h1.w};
        float sum = 0.f;
#pragma unroll
        for (int m = 0; m < 8; ++m) {
          const float nh = ((1.0f - sv[m]) * hv[m] + sv[m] * qv) * c_decay[m];
          hv[m] = nh;
          sum += nh;
        }
        *(float4*)(h_hat + base)     = make_float4(hv[0], hv[1], hv[2], hv[3]);
        *(float4*)(h_hat + base + 4) = make_float4(hv[4], hv[5], hv[6], hv[7]);
        const unsigned short sh = f2bf(sum);
        Ahw[(size_t)b * Kdim + Fdim + u] = (short)sh;
        Alw[(size_t)b * Kdim + Fdim + u] = (short)f2bf(sum - bf2f(sh));
      }
}

// ---------------------------------------------------------------------------
// out[b,t,:] = h[b,:] @ Wo + bo  (h reconstructed hi+lo); fused x-split for t+1
// ---------------------------------------------------------------------------
__global__ __launch_bounds__(64)
void out_step(const short* Ahg, const short* Alg,
              const float* __restrict__ Wo, const float* __restrict__ bo,
              float* __restrict__ out, const float* __restrict__ x,
              short* Ahw, short* Alw, int t)
{
  const int b = blockIdx.x, lane = threadIdx.x;
  const short* hh = Ahg + (size_t)b * Kdim + Fdim;
  const short* hl = Alg + (size_t)b * Kdim + Fdim;
  float a0 = 0.f, a1 = 0.f, a2 = 0.f;
#pragma unroll
  for (int u0 = 0; u0 < Udim; u0 += 64) {
    const int u = u0 + lane;
    const float hv = bf2f((unsigned short)hh[u]) + bf2f((unsigned short)hl[u]);
    const float* w = Wo + (size_t)u * 3;
    a0 = fmaf(hv, w[0], a0);
    a1 = fmaf(hv, w[1], a1);
    a2 = fmaf(hv, w[2], a2);
  }
#pragma unroll
  for (int off = 32; off; off >>= 1) {
    a0 += __shfl_down(a0, off);
    a1 += __shfl_down(a1, off);
    a2 += __shfl_down(a2, off);
  }
  if (lane == 0) {
    float* o = out + ((size_t)b * Tdim + t) * 3;
    o[0] = a0 + bo[0]; o[1] = a1 + bo[1]; o[2] = a2 + bo[2];
  }
  if (t + 1 < Tdim) xsplit_row(x, Ahw, Alw, b, t + 1, lane);
}

__global__ __launch_bounds__(256)
void zero_kernel(float4* __restrict__ p, size_t n4)
{
  const size_t i = (size_t)blockIdx.x * 256 + threadIdx.x;
  const size_t stride = (size_t)gridDim.x * 256;
  for (size_t j = i; j < n4; j += stride)
    p[j] = make_float4(0.f, 0.f, 0.f, 0.f);
}

extern "C" void kernel_launch(void* const* d_in, const int* in_sizes, int n_in,
                              void* d_out, int out_size, void* d_ws, size_t ws_size,
                              hipStream_t stream)
{
  const float* x  = (const float*)d_in[0];
  const float* Wr = (const float*)d_in[1];
  const float* br = (const float*)d_in[2];
  const float* Wq = (const float*)d_in[3];
  const float* bq = (const float*)d_in[4];
  const float* Ws = (const float*)d_in[5];
  const float* bs = (const float*)d_in[6];
  const float* Wo = (const float*)d_in[7];
  const float* bo = (const float*)d_in[8];
  float* out = (float*)d_out;

  // ws layout (bytes) — totals EXACTLY 159,383,552 (proven available in R3):
  //   WTh/WTl [8192][1024] bf16 : 2 x 16,777,216
  //   Ahg/Alg [4096][1024] bf16 : 2 x  8,388,608   (cols 0-511 = x_t, 512-1023 = h)
  //   Ch/Cl   [4096][512]  bf16 : 2 x  4,194,304   (ctx split)
  //   hhat    [B][U][M]    f32  :     67,108,864
  //   sbuf    [B][U][M]    f16  :     33,554,432
  const size_t need = 159383552;
  if (ws_size < need) return;

  char* p = (char*)d_ws;
  short* WTh = (short*)p;  p += 16777216;
  short* WTl = (short*)p;  p += 16777216;
  short* Ahg = (short*)p;  p += 8388608;
  short* Alg = (short*)p;  p += 8388608;
  short* Ch  = (short*)p;  p += 4194304;
  short* Cl  = (short*)p;  p += 4194304;
  float* hhat = (float*)p; p += 67108864;
  __half* sbuf = (__half*)p;

  zero_kernel<<<2048, 256, 0, stream>>>((float4*)hhat, 4194304);
  wconv<<<dim3(64, 16), 256, 0, stream>>>(Wr, 4096, WTh, WTl, 0);
  wconv<<<dim3(64, 16), 256, 0, stream>>>(Ws, 4096, WTh, WTl, 4096);
  xsplit0<<<4096, 64, 0, stream>>>(x, Ahg, Alg);

  for (int t = 0; t < Tdim; ++t) {
    const int kmax = t ? Kdim : Fdim;   // t=0: h=0, ctx=0 exactly -> skip dead half
    gemm_rs_mfma<<<dim3(64, 32), 256, 0, stream>>>(Ahg, Alg, WTh, WTl, br, bs,
                                                   hhat, Ch, Cl, sbuf, kmax);
    gemm_q_mfma<<<dim3(4, 64), 256, 0, stream>>>(Ahg, Alg, Ch, Cl, Wq, bq,
                                                 sbuf, hhat, Ahg, Alg, kmax);
    out_step<<<4096, 64, 0, stream>>>(Ahg, Alg, Wo, bo, out, x, Ahg, Alg, t);
  }
}